// Round 6
// baseline (2929.755 us; speedup 1.0000x reference)
//
#include <hip/hip_runtime.h>
#include <hip/hip_bf16.h>

#define DIM 128   // D
#define K2  256   // 2*D (q_star width)
#define G4  512   // 4*D (gate width)
#define NITERS 6

typedef __attribute__((ext_vector_type(8))) __bf16 bf16x8;
typedef __attribute__((ext_vector_type(2))) __bf16 bf16x2;
typedef __attribute__((ext_vector_type(4))) float  f32x4;

__device__ __forceinline__ float sigmoidf_fast(float x) {
    return 1.0f / (1.0f + __expf(-x));
}
// robust at both tails: x->+inf => 1, x->-inf => -1
__device__ __forceinline__ float tanhf_fast(float x) {
    return 1.0f - 2.0f / (__expf(2.0f * x) + 1.0f);
}

// seg[b] = first n with batch[n] >= b (batch sorted). seg[B] = N.
__global__ void seg_offsets_kernel(const int* __restrict__ batch,
                                   int* __restrict__ seg, int N, int B) {
    int n = blockIdx.x * blockDim.x + threadIdx.x;
    if (n >= N) return;
    int b  = batch[n];
    int bp = (n == 0) ? -1 : batch[n - 1];
    for (int k = bp + 1; k <= b; ++k) seg[k] = n;
    if (n == N - 1) {
        for (int k = b + 1; k <= B; ++k) seg[k] = N;
    }
}

// Wc[g][k] = w_ih[g][k] + (k<128 ? w_hh[g][k] : 0), as bf16. biasc = b_ih + b_hh.
__global__ void build_w_kernel(const float* __restrict__ w_ih,
                               const float* __restrict__ w_hh,
                               const float* __restrict__ b_ih,
                               const float* __restrict__ b_hh,
                               __bf16* __restrict__ Wc,
                               float* __restrict__ biasc) {
    int idx = blockIdx.x * blockDim.x + threadIdx.x;
    if (idx >= G4 * K2) return;
    int g = idx >> 8;
    int j = idx & 255;
    float v = w_ih[idx];
    if (j < DIM) v += w_hh[g * DIM + j];
    Wc[idx] = (__bf16)v;
    if (idx < G4) biasc[idx] = b_ih[idx] + b_hh[idx];
}

// One wave computes a 16-row x 16-j tile of all four gates (i,f,g,o), K=256 via
// 8 MFMA steps per gate. q_star input = [h_in | ro_in] bf16. Outputs: c (fp32,
// in-place), h fp32 into outbuf[row*256 + j], h bf16 into h_out.
__global__ __launch_bounds__(256) void lstm_kernel(
    const __bf16* __restrict__ h_in,    // [B][128]
    const __bf16* __restrict__ ro_in,   // [B][128]
    const __bf16* __restrict__ Wc,      // [512][256]
    const float*  __restrict__ biasc,   // [512]
    float* __restrict__ c,              // [B][128]
    float* __restrict__ outbuf,         // d_out: h lives at [row*256 + j]
    __bf16* __restrict__ h_out,         // [B][128]
    int B)
{
    int lane = threadIdx.x & 63;
    int wid  = (blockIdx.x * blockDim.x + threadIdx.x) >> 6;
    int rt = wid >> 3;          // row tile
    int jb = wid & 7;           // j block (0..7), 16 js each
    int r0 = rt * 16;
    if (r0 >= B) return;
    int l15 = lane & 15;
    int lhi = lane >> 4;
    int j0  = jb * 16 + l15;    // this lane's output column within [0,128)

    float bI = biasc[0 * DIM + j0];
    float bF = biasc[1 * DIM + j0];
    float bG = biasc[2 * DIM + j0];
    float bO = biasc[3 * DIM + j0];
    f32x4 accI = {bI, bI, bI, bI};
    f32x4 accF = {bF, bF, bF, bF};
    f32x4 accG = {bG, bG, bG, bG};
    f32x4 accO = {bO, bO, bO, bO};

    int arow = r0 + l15;
    if (arow >= B) arow = B - 1;   // safe clamp; results for rows>=B discarded
    const __bf16* aph = h_in  + (size_t)arow * DIM + lhi * 8;
    const __bf16* apr = ro_in + (size_t)arow * DIM + lhi * 8;
    const __bf16* bpI = Wc + (size_t)(0 * DIM + j0) * K2 + lhi * 8;
    const __bf16* bpF = Wc + (size_t)(1 * DIM + j0) * K2 + lhi * 8;
    const __bf16* bpG = Wc + (size_t)(2 * DIM + j0) * K2 + lhi * 8;
    const __bf16* bpO = Wc + (size_t)(3 * DIM + j0) * K2 + lhi * 8;

#pragma unroll
    for (int kb = 0; kb < 8; ++kb) {
        int ko = (kb & 3) * 32;
        bf16x8 a  = *(const bf16x8*)((kb < 4 ? aph : apr) + ko);
        bf16x8 vI = *(const bf16x8*)(bpI + kb * 32);
        bf16x8 vF = *(const bf16x8*)(bpF + kb * 32);
        bf16x8 vG = *(const bf16x8*)(bpG + kb * 32);
        bf16x8 vO = *(const bf16x8*)(bpO + kb * 32);
        accI = __builtin_amdgcn_mfma_f32_16x16x32_bf16(a, vI, accI, 0, 0, 0);
        accF = __builtin_amdgcn_mfma_f32_16x16x32_bf16(a, vF, accF, 0, 0, 0);
        accG = __builtin_amdgcn_mfma_f32_16x16x32_bf16(a, vG, accG, 0, 0, 0);
        accO = __builtin_amdgcn_mfma_f32_16x16x32_bf16(a, vO, accO, 0, 0, 0);
    }

#pragma unroll
    for (int r = 0; r < 4; ++r) {
        int row = r0 + lhi * 4 + r;   // D row = (lane>>4)*4 + reg  [verified m89/m91]
        if (row >= B) continue;
        int col = j0;
        float ig = sigmoidf_fast(accI[r]);
        float fg = sigmoidf_fast(accF[r]);
        float gg = tanhf_fast(accG[r]);
        float og = sigmoidf_fast(accO[r]);
        size_t cidx = (size_t)row * DIM + col;
        float cold = c[cidx];
        float cn = fg * cold + ig * gg;
        float hv = og * tanhf_fast(cn);
        c[cidx] = cn;
        outbuf[(size_t)row * K2 + col] = hv;
        h_out[cidx] = (__bf16)hv;
    }
}

// One wave per segment: flash-style online softmax + weighted accumulation.
// x read exactly once per iteration.
__global__ __launch_bounds__(256) void attn_kernel(
    const float* __restrict__ x,      // [N][128]
    const float* __restrict__ hbuf,   // d_out: h at [b*256 + j]
    const int*   __restrict__ seg,    // [B+1]
    __bf16* __restrict__ ro_out,      // [B][128]
    float*  __restrict__ out_f32,     // d_out: readout at [b*256 + 128 + j]
    int B)
{
    int lane = threadIdx.x & 63;
    int b = (blockIdx.x * blockDim.x + threadIdx.x) >> 6;
    if (b >= B) return;
    int n0 = seg[b], n1 = seg[b + 1];

    float2 h2 = *(const float2*)(hbuf + (size_t)b * K2 + 2 * lane);

    float m = -3.4e38f, den = 0.0f, a0 = 0.0f, a1 = 0.0f;
    for (int n = n0; n < n1; ++n) {
        float2 xv = *(const float2*)(x + (size_t)n * DIM + 2 * lane);
        float p = xv.x * h2.x + xv.y * h2.y;
        p += __shfl_xor(p, 32); p += __shfl_xor(p, 16); p += __shfl_xor(p, 8);
        p += __shfl_xor(p, 4);  p += __shfl_xor(p, 2);  p += __shfl_xor(p, 1);
        float mn = fmaxf(m, p);
        float s  = __expf(m - mn);   // first iter: exp(-inf) = 0
        float w  = __expf(p - mn);
        den = den * s + w;
        a0  = a0 * s + w * xv.x;
        a1  = a1 * s + w * xv.y;
        m = mn;
    }
    float r0v = 0.0f, r1v = 0.0f;
    if (n1 > n0) {
        float inv = 1.0f / den;
        r0v = a0 * inv;
        r1v = a1 * inv;
    }
    bf16x2 rb = {(__bf16)r0v, (__bf16)r1v};
    *(bf16x2*)(ro_out + (size_t)b * DIM + 2 * lane) = rb;
    float2 rf = make_float2(r0v, r1v);
    *(float2*)(out_f32 + (size_t)b * K2 + DIM + 2 * lane) = rf;
}

extern "C" void kernel_launch(void* const* d_in, const int* in_sizes, int n_in,
                              void* d_out, int out_size, void* d_ws, size_t ws_size,
                              hipStream_t stream) {
    const float* x     = (const float*)d_in[0];
    const int*   batch = (const int*)d_in[1];
    const float* w_ih  = (const float*)d_in[2];
    const float* w_hh  = (const float*)d_in[3];
    const float* b_ih  = (const float*)d_in[4];
    const float* b_hh  = (const float*)d_in[5];

    int N = in_sizes[0] / DIM;   // 1,000,000
    int B = out_size / K2;       // 100,000
    float* out = (float*)d_out;

    char* ws = (char*)d_ws;
    size_t off = 0;
    auto walloc = [&](size_t bytes) -> void* {
        void* p = ws + off;
        off += (bytes + 255) & ~(size_t)255;
        return p;
    };
    __bf16* hbuf0 = (__bf16*)walloc((size_t)B * DIM * 2);
    __bf16* hbuf1 = (__bf16*)walloc((size_t)B * DIM * 2);
    __bf16* robuf = (__bf16*)walloc((size_t)B * DIM * 2);
    float*  cbuf  = (float*) walloc((size_t)B * DIM * 4);
    __bf16* Wc    = (__bf16*)walloc((size_t)G4 * K2 * 2);
    float*  biasc = (float*) walloc((size_t)G4 * 4);
    int*    seg   = (int*)   walloc((size_t)(B + 1) * 4);
    (void)ws_size;

    // zero initial state (ws is poisoned 0xAA before every launch)
    hipMemsetAsync(hbuf0, 0, (size_t)B * DIM * 2, stream);
    hipMemsetAsync(robuf, 0, (size_t)B * DIM * 2, stream);
    hipMemsetAsync(cbuf,  0, (size_t)B * DIM * 4, stream);

    seg_offsets_kernel<<<(N + 255) / 256, 256, 0, stream>>>(batch, seg, N, B);
    build_w_kernel<<<(G4 * K2 + 255) / 256, 256, 0, stream>>>(w_ih, w_hh, b_ih, b_hh, Wc, biasc);

    int rtiles = (B + 15) / 16;
    int lstm_blocks = (rtiles * 8 + 3) / 4;   // 4 waves per 256-thread block
    int attn_blocks = (B + 3) / 4;

    for (int t = 0; t < NITERS; ++t) {
        const __bf16* hin = (t & 1) ? hbuf1 : hbuf0;
        __bf16* hout      = (t & 1) ? hbuf0 : hbuf1;
        lstm_kernel<<<lstm_blocks, 256, 0, stream>>>(hin, robuf, Wc, biasc,
                                                     cbuf, out, hout, B);
        attn_kernel<<<attn_blocks, 256, 0, stream>>>(x, out, seg, robuf, out, B);
    }
}